// Round 8
// baseline (29.210 us; speedup 1.0000x reference)
//
#include <hip/hip_runtime.h>

// PoolingAggregator: out[b,g] = mean over {t : segment_ids[t]==g} of feat[b, flat_indices[t]]
// B=512, N=10000, G=2048, T=131072.
//
// Pipeline (2 kernels; R6 base = best measured 26.5us):
//   k1 "prep": grid (157, 9).
//       y<8 : transpose+convert feat (B,N) f32 -> featT (N,512) bf16, 64x64 tiles.
//       y==8: offs[g] = lower_bound(segment_ids, g) via linear boundary scan.
//   k2 "gather" (R8 change): 4 B-chunks of 128 floats (256B bf16 slices) instead of
//       8x64 -> each slot-group request is 256B contiguous, HALVING the L2 request
//       count (2.1M->1.05M) at constant bytes. chunk = blockIdx&3; per-XCD slice
//       2.56MB (L2-fit). grid (G/4)*4 = 2048 blocks = 32 waves/CU in one round.
//       Per 64-idx window: one coalesced idx load (prefetched), shfl address
//       broadcast, 16 rounds x 4 slots of 256B loads. bf16 accumulate keeps
//       hi-half garbage bits (~1e-3 << 1.28e-2 threshold). shfl_xor slot reduce,
//       4x128 LDS tile, float4 store.

__device__ __forceinline__ unsigned bf16rne(float f) {
    unsigned u = __float_as_uint(f);
    return (u + 0x7fffu + ((u >> 16) & 1u)) >> 16;
}

// grid (ceil(N/64), 9), 256 threads.
__global__ __launch_bounds__(256) void pa_prep(const float* __restrict__ feat,
                                               const int* __restrict__ seg,
                                               unsigned short* __restrict__ featT,
                                               int* __restrict__ offs,
                                               int N, int T, int G, int nXBlocks) {
    if (blockIdx.y == 8) {
        int stride = nXBlocks * 256;
        for (int t = blockIdx.x * 256 + threadIdx.x; t < T; t += stride) {
            int cur  = seg[t];
            int prev = (t == 0) ? -1 : seg[t - 1];
            for (int g = prev + 1; g <= cur; ++g) offs[g] = t;
            if (t == T - 1) {
                for (int g = cur + 1; g <= G; ++g) offs[g] = T;
            }
        }
        return;
    }

    // ---- transpose 64(b) x 64(n) tile ----
    __shared__ float tile[64][65];
    const int n0 = blockIdx.x * 64;
    const int b0 = blockIdx.y * 64;
    const int tid = threadIdx.x;
    const int r  = tid >> 4;   // 0..15
    const int c4 = tid & 15;   // float4 column

    if (n0 + 64 <= N) {
        #pragma unroll
        for (int i = 0; i < 4; ++i) {
            int b = r + 16 * i;
            const float4 v = *(const float4*)&feat[(size_t)(b0 + b) * N + n0 + c4 * 4];
            tile[b][c4 * 4 + 0] = v.x;
            tile[b][c4 * 4 + 1] = v.y;
            tile[b][c4 * 4 + 2] = v.z;
            tile[b][c4 * 4 + 3] = v.w;
        }
    } else {
        #pragma unroll
        for (int i = 0; i < 4; ++i) {
            int b = r + 16 * i;
            #pragma unroll
            for (int j = 0; j < 4; ++j) {
                int n = n0 + c4 * 4 + j;
                tile[b][c4 * 4 + j] = (n < N) ? feat[(size_t)(b0 + b) * N + n] : 0.0f;
            }
        }
    }
    __syncthreads();

    uint2* outu = (uint2*)featT;  // row = 128 uint2 (512 bf16)
    #pragma unroll
    for (int i = 0; i < 4; ++i) {
        int nl = r + 16 * i;
        int n = n0 + nl;
        if (n >= N) continue;
        uint2 u;
        u.x = bf16rne(tile[c4 * 4 + 0][nl]) | (bf16rne(tile[c4 * 4 + 1][nl]) << 16);
        u.y = bf16rne(tile[c4 * 4 + 2][nl]) | (bf16rne(tile[c4 * 4 + 3][nl]) << 16);
        outu[(size_t)n * 128 + (b0 >> 2) + c4] = u;
    }
}

// Accumulate 8 bf16 (one uint4). Hi halves keep low-bit garbage (<=1 ulp_bf16/term).
#define ACC8(v)                                   \
    do {                                          \
        a0 += __uint_as_float((v).x << 16);       \
        a1 += __uint_as_float((v).x);             \
        a2 += __uint_as_float((v).y << 16);       \
        a3 += __uint_as_float((v).y);             \
        a4 += __uint_as_float((v).z << 16);       \
        a5 += __uint_as_float((v).z);             \
        a6 += __uint_as_float((v).w << 16);       \
        a7 += __uint_as_float((v).w);             \
    } while (0)

// grid = (G/4)*4 = 2048 blocks, 256 threads (4 waves). Block b: chunk=b&3, i=b>>2.
// Wave w: group g = i*4+w. Slot = lane>>4 (4 idx-parallel), lane_b = lane&15
// (16 lanes x 16B = 256B contiguous slice of the 128-float chunk).
__global__ __launch_bounds__(256) void pa_gather_mean_bf16(
    const unsigned short* __restrict__ featT,  // (N, 512) bf16
    const int* __restrict__ idxs,              // (T,)
    const int* __restrict__ offs,              // (G+1,)
    float* __restrict__ out,                   // (B, G)
    int G) {
    const int chunk = blockIdx.x & 3;
    const int i     = blockIdx.x >> 2;
    const int wave  = threadIdx.x >> 6;
    const int lane  = threadIdx.x & 63;
    const int lane_b = lane & 15;
    const int slot   = lane >> 4;
    const int g      = i * 4 + wave;

    const int s = offs[g];
    const int e = offs[g + 1];
    const int cnt = e - s;

    // lane base: chunk*256B + lane_b*16B; row stride 1024B
    const char* __restrict__ fbase = (const char*)featT + chunk * 256 + lane_b * 16;

    float a0 = 0.f, a1 = 0.f, a2 = 0.f, a3 = 0.f,
          a4 = 0.f, a5 = 0.f, a6 = 0.f, a7 = 0.f;

    int w = s;
    int nrem = cnt;
    int myidx = (s + lane < e) ? idxs[s + lane] : 0;

    // full 64-index windows: no predication, next window's indices prefetched
    while (nrem >= 64) {
        int cur = myidx;
        w += 64;
        nrem -= 64;
        if (nrem > 0) myidx = (w + lane < e) ? idxs[w + lane] : 0;
        #pragma unroll
        for (int k = 0; k < 16; ++k) {
            int ridx = __shfl(cur, slot + 4 * k);
            uint4 v = *(const uint4*)(fbase + ((size_t)(unsigned)(ridx << 10)));
            ACC8(v);
        }
    }
    // tail (< 64 indices), masked
    if (nrem > 0) {
        int cur = myidx;
        #pragma unroll
        for (int k = 0; k < 16; ++k) {
            int li = slot + 4 * k;
            int ridx = __shfl(cur, li);
            if (li < nrem) {
                uint4 v = *(const uint4*)(fbase + ((size_t)(unsigned)(ridx << 10)));
                ACC8(v);
            }
        }
    }

    // reduce over the 4 slots (lane bits 4,5)
    a0 += __shfl_xor(a0, 16); a0 += __shfl_xor(a0, 32);
    a1 += __shfl_xor(a1, 16); a1 += __shfl_xor(a1, 32);
    a2 += __shfl_xor(a2, 16); a2 += __shfl_xor(a2, 32);
    a3 += __shfl_xor(a3, 16); a3 += __shfl_xor(a3, 32);
    a4 += __shfl_xor(a4, 16); a4 += __shfl_xor(a4, 32);
    a5 += __shfl_xor(a5, 16); a5 += __shfl_xor(a5, 32);
    a6 += __shfl_xor(a6, 16); a6 += __shfl_xor(a6, 32);
    a7 += __shfl_xor(a7, 16); a7 += __shfl_xor(a7, 32);

    __shared__ float gtile[4][128];
    if (slot == 0) {
        float inv = 1.0f / (float)(cnt > 0 ? cnt : 1);
        int bl = lane_b * 8;
        gtile[wave][bl + 0] = a0 * inv;
        gtile[wave][bl + 1] = a1 * inv;
        gtile[wave][bl + 2] = a2 * inv;
        gtile[wave][bl + 3] = a3 * inv;
        gtile[wave][bl + 4] = a4 * inv;
        gtile[wave][bl + 5] = a5 * inv;
        gtile[wave][bl + 6] = a6 * inv;
        gtile[wave][bl + 7] = a7 * inv;
    }
    __syncthreads();

    // store: threads 0..127 -> row = tid, float4 across the block's 4 groups
    if (threadIdx.x < 128) {
        int rrow = threadIdx.x;
        float4 r4;
        r4.x = gtile[0][rrow];
        r4.y = gtile[1][rrow];
        r4.z = gtile[2][rrow];
        r4.w = gtile[3][rrow];
        *(float4*)&out[(size_t)(chunk * 128 + rrow) * G + i * 4] = r4;
    }
}

// Fallback for unexpected shapes (correct but slow).
__global__ __launch_bounds__(256) void pa_group_mean_direct(
    const float* __restrict__ feat, const int* __restrict__ flat_indices,
    const int* __restrict__ segment_ids, float* __restrict__ out,
    int T, int B, int N, int G) {
    const int g = blockIdx.x;
    const int tid = threadIdx.x;
    __shared__ int sb[2];
    __shared__ int s_idx[256];
    if (tid < 2) {
        int target = g + tid;
        int lo = 0, hi = T;
        while (lo < hi) {
            int mid = (lo + hi) >> 1;
            if (segment_ids[mid] < target) lo = mid + 1; else hi = mid;
        }
        sb[tid] = lo;
    }
    __syncthreads();
    const int s = sb[0], e = sb[1];
    const int cnt = e - s;
    int p0 = tid * 2, p1 = tid * 2 + 1;
    float x0 = 0.f, x1 = 0.f;
    for (int base = s; base < e; base += 256) {
        int k = base + tid;
        if (k < e) s_idx[tid] = flat_indices[k];
        __syncthreads();
        int m = min(256, e - base);
        for (int jj = 0; jj < m; ++jj) {
            int idx = s_idx[jj];
            if (p0 < B) x0 += feat[(long)p0 * N + idx];
            if (p1 < B) x1 += feat[(long)p1 * N + idx];
        }
        __syncthreads();
    }
    float inv = 1.0f / (float)(cnt > 0 ? cnt : 1);
    if (p0 < B) out[(long)p0 * G + g] = x0 * inv;
    if (p1 < B) out[(long)p1 * G + g] = x1 * inv;
}

extern "C" void kernel_launch(void* const* d_in, const int* in_sizes, int n_in,
                              void* d_out, int out_size, void* d_ws, size_t ws_size,
                              hipStream_t stream) {
    const float* feat          = (const float*)d_in[0];
    const int*   flat_indices  = (const int*)d_in[1];
    const int*   segment_ids   = (const int*)d_in[2];
    float*       out           = (float*)d_out;

    const int B = 512;
    const int N = in_sizes[0] / B;      // 10000
    const int T = in_sizes[1];          // 131072
    const int G = out_size / B;         // 2048

    size_t featT_bytes = (size_t)N * B * sizeof(unsigned short);
    size_t need = featT_bytes + (size_t)(G + 1) * sizeof(int);
    if (ws_size >= need && B == 512 && (G % 4) == 0 && T >= 1) {
        unsigned short* featT = (unsigned short*)d_ws;            // (N, 512) bf16
        int* offs = (int*)((char*)d_ws + featT_bytes);            // (G+1,)

        int nXBlocks = (N + 63) / 64;  // 157
        dim3 g1(nXBlocks, 9);
        pa_prep<<<g1, 256, 0, stream>>>(feat, segment_ids, featT, offs, N, T, G, nXBlocks);

        pa_gather_mean_bf16<<<(G / 4) * 4, 256, 0, stream>>>(featT, flat_indices, offs,
                                                             out, G);
    } else {
        pa_group_mean_direct<<<G, 256, 0, stream>>>(feat, flat_indices, segment_ids,
                                                    out, T, B, N, G);
    }
}

// Round 9
// 25.829 us; speedup vs baseline: 1.1309x; 1.1309x over previous
//
#include <hip/hip_runtime.h>

// PoolingAggregator: out[b,g] = mean over {t : segment_ids[t]==g} of feat[b, flat_indices[t]]
// B=512, N=10000, G=2048, T=131072.
//
// Pipeline (2 kernels, single-round grids):
//   k1 "prep": EXACTLY 1024 blocks (4/CU, one round). Task tau = tile*8+chunk over
//       nTiles*8=1256 tile-tasks: block x does tau=x and tau=x+1024 (x<232).
//       Blocks 867..1023 additionally run the offs[] linear boundary scan (independent
//       of the transpose, no sync needed). 64x64 f32->bf16 transpose tiles.
//   k2 "gather": EXACTLY 2048 blocks (8/CU, one round). Block b: chunk=b&7 (XCD
//       round-robin, 1.28MB featT slice L2-pinned), i=b>>3; wave w handles groups
//       i*8+2w, i*8+2w+1 SEQUENTIALLY. Per 64-idx window: coalesced idx load
//       (prefetched), shfl address broadcast, 8 independent 128B row loads,
//       float2-packed accumulate (v_pk_add_f32; hi halves keep low-bit garbage,
//       error ~1e-3 << 1.28e-2 threshold). shfl_xor slot reduce, 8x64 LDS tile,
//       float2 stores.

__device__ __forceinline__ unsigned bf16rne(float f) {
    unsigned u = __float_as_uint(f);
    return (u + 0x7fffu + ((u >> 16) & 1u)) >> 16;
}

// grid 1024 x 256.
__global__ __launch_bounds__(256) void pa_prep(const float* __restrict__ feat,
                                               const int* __restrict__ seg,
                                               unsigned short* __restrict__ featT,
                                               int* __restrict__ offs,
                                               int N, int T, int G, int nTiles) {
    const int x = blockIdx.x;
    const int nTr = nTiles * 8;  // 1256 tile-tasks
    const int tid = threadIdx.x;

    __shared__ float tile[64][65];
    const int r  = tid >> 4;   // 0..15
    const int c4 = tid & 15;   // float4 column

    for (int tau = x; tau < nTr; tau += 1024) {
        const int c  = tau & 7;
        const int n0 = (tau >> 3) * 64;
        const int b0 = c * 64;

        if (n0 + 64 <= N) {
            #pragma unroll
            for (int i = 0; i < 4; ++i) {
                int b = r + 16 * i;
                const float4 v = *(const float4*)&feat[(size_t)(b0 + b) * N + n0 + c4 * 4];
                tile[b][c4 * 4 + 0] = v.x;
                tile[b][c4 * 4 + 1] = v.y;
                tile[b][c4 * 4 + 2] = v.z;
                tile[b][c4 * 4 + 3] = v.w;
            }
        } else {
            #pragma unroll
            for (int i = 0; i < 4; ++i) {
                int b = r + 16 * i;
                #pragma unroll
                for (int j = 0; j < 4; ++j) {
                    int n = n0 + c4 * 4 + j;
                    tile[b][c4 * 4 + j] = (n < N) ? feat[(size_t)(b0 + b) * N + n] : 0.0f;
                }
            }
        }
        __syncthreads();

        uint2* outu = (uint2*)featT;  // row = 128 uint2 (512 bf16)
        #pragma unroll
        for (int i = 0; i < 4; ++i) {
            int nl = r + 16 * i;
            int n = n0 + nl;
            if (n < N) {
                uint2 u;
                u.x = bf16rne(tile[c4 * 4 + 0][nl]) | (bf16rne(tile[c4 * 4 + 1][nl]) << 16);
                u.y = bf16rne(tile[c4 * 4 + 2][nl]) | (bf16rne(tile[c4 * 4 + 3][nl]) << 16);
                outu[(size_t)n * 128 + (b0 >> 2) + c4] = u;
            }
        }
        __syncthreads();
    }

    // offs boundary scan on 157 single-tile blocks (867..1023)
    const int sBase = 1024 - 157;  // 867
    if (x >= sBase) {
        int s = x - sBase;
        for (int t = s * 256 + tid; t < T; t += 157 * 256) {
            int cur  = seg[t];
            int prev = (t == 0) ? -1 : seg[t - 1];
            for (int g = prev + 1; g <= cur; ++g) offs[g] = t;
            if (t == T - 1) {
                for (int g = cur + 1; g <= G; ++g) offs[g] = T;
            }
        }
    }
}

// Accumulate 8 bf16 (one uint4) into 4 float2 accs as {lo<<16, raw} pairs ->
// 1 shift + 1 v_pk_add_f32 per uint. Hi halves keep low-bit garbage (<=1 ulp_bf16).
#define ACC8(v)                                                          \
    do {                                                                 \
        A0.x += __uint_as_float((v).x << 16); A0.y += __uint_as_float((v).x); \
        A1.x += __uint_as_float((v).y << 16); A1.y += __uint_as_float((v).y); \
        A2.x += __uint_as_float((v).z << 16); A2.y += __uint_as_float((v).z); \
        A3.x += __uint_as_float((v).w << 16); A3.y += __uint_as_float((v).w); \
    } while (0)

#define RED8(a) \
    a += __shfl_xor(a, 8); a += __shfl_xor(a, 16); a += __shfl_xor(a, 32)

// grid = (G/8)*8 = 2048 blocks, 256 threads (4 waves), one round (8 blocks/CU).
// Block b: chunk=b&7, i=b>>3. Wave w: groups i*8+2w, i*8+2w+1 sequentially.
__global__ __launch_bounds__(256) void pa_gather_mean_bf16(
    const unsigned short* __restrict__ featT,  // (N, 512) bf16
    const int* __restrict__ idxs,              // (T,)
    const int* __restrict__ offs,              // (G+1,)
    float* __restrict__ out,                   // (B, G)
    int G) {
    const int chunk = blockIdx.x & 7;
    const int i     = blockIdx.x >> 3;
    const int wave  = threadIdx.x >> 6;
    const int lane  = threadIdx.x & 63;
    const int lane_b = lane & 7;
    const int slot   = lane >> 3;

    const char* __restrict__ fbase = (const char*)featT + chunk * 128 + lane_b * 16;

    __shared__ float gtile[8][64];

    #pragma unroll
    for (int q = 0; q < 2; ++q) {
        const int g = i * 8 + wave * 2 + q;
        const int s = offs[g];
        const int e = offs[g + 1];
        const int cnt = e - s;

        float2 A0 = make_float2(0.f, 0.f), A1 = make_float2(0.f, 0.f),
               A2 = make_float2(0.f, 0.f), A3 = make_float2(0.f, 0.f);

        int w = s;
        int nrem = cnt;
        int myidx = (s + lane < e) ? idxs[s + lane] : 0;

        while (nrem >= 64) {
            int cur = myidx;
            w += 64;
            nrem -= 64;
            if (nrem > 0) myidx = (w + lane < e) ? idxs[w + lane] : 0;
            #pragma unroll
            for (int k = 0; k < 8; ++k) {
                int ridx = __shfl(cur, slot + 8 * k);
                uint4 v = *(const uint4*)(fbase + ((size_t)(unsigned)(ridx << 10)));
                ACC8(v);
            }
        }
        if (nrem > 0) {
            int cur = myidx;
            #pragma unroll
            for (int k = 0; k < 8; ++k) {
                int li = slot + 8 * k;
                int ridx = __shfl(cur, li);
                if (li < nrem) {
                    uint4 v = *(const uint4*)(fbase + ((size_t)(unsigned)(ridx << 10)));
                    ACC8(v);
                }
            }
        }

        RED8(A0.x); RED8(A0.y); RED8(A1.x); RED8(A1.y);
        RED8(A2.x); RED8(A2.y); RED8(A3.x); RED8(A3.y);

        if (slot == 0) {
            float inv = 1.0f / (float)(cnt > 0 ? cnt : 1);
            int rrow = wave * 2 + q;
            int bl = lane_b * 8;
            gtile[rrow][bl + 0] = A0.x * inv;
            gtile[rrow][bl + 1] = A0.y * inv;
            gtile[rrow][bl + 2] = A1.x * inv;
            gtile[rrow][bl + 3] = A1.y * inv;
            gtile[rrow][bl + 4] = A2.x * inv;
            gtile[rrow][bl + 5] = A2.y * inv;
            gtile[rrow][bl + 6] = A3.x * inv;
            gtile[rrow][bl + 7] = A3.y * inv;
        }
    }
    __syncthreads();

    // store: thread t -> b_local = t>>2, group-pair gp = t&3 (float2 = 2 consecutive g)
    int bb = threadIdx.x >> 2;
    int gp = threadIdx.x & 3;
    float2 r2;
    r2.x = gtile[gp * 2 + 0][bb];
    r2.y = gtile[gp * 2 + 1][bb];
    *(float2*)&out[(size_t)(chunk * 64 + bb) * G + i * 8 + gp * 2] = r2;
}

// Fallback for unexpected shapes (correct but slow).
__global__ __launch_bounds__(256) void pa_group_mean_direct(
    const float* __restrict__ feat, const int* __restrict__ flat_indices,
    const int* __restrict__ segment_ids, float* __restrict__ out,
    int T, int B, int N, int G) {
    const int g = blockIdx.x;
    const int tid = threadIdx.x;
    __shared__ int sb[2];
    __shared__ int s_idx[256];
    if (tid < 2) {
        int target = g + tid;
        int lo = 0, hi = T;
        while (lo < hi) {
            int mid = (lo + hi) >> 1;
            if (segment_ids[mid] < target) lo = mid + 1; else hi = mid;
        }
        sb[tid] = lo;
    }
    __syncthreads();
    const int s = sb[0], e = sb[1];
    const int cnt = e - s;
    int p0 = tid * 2, p1 = tid * 2 + 1;
    float x0 = 0.f, x1 = 0.f;
    for (int base = s; base < e; base += 256) {
        int k = base + tid;
        if (k < e) s_idx[tid] = flat_indices[k];
        __syncthreads();
        int m = min(256, e - base);
        for (int jj = 0; jj < m; ++jj) {
            int idx = s_idx[jj];
            if (p0 < B) x0 += feat[(long)p0 * N + idx];
            if (p1 < B) x1 += feat[(long)p1 * N + idx];
        }
        __syncthreads();
    }
    float inv = 1.0f / (float)(cnt > 0 ? cnt : 1);
    if (p0 < B) out[(long)p0 * G + g] = x0 * inv;
    if (p1 < B) out[(long)p1 * G + g] = x1 * inv;
}

extern "C" void kernel_launch(void* const* d_in, const int* in_sizes, int n_in,
                              void* d_out, int out_size, void* d_ws, size_t ws_size,
                              hipStream_t stream) {
    const float* feat          = (const float*)d_in[0];
    const int*   flat_indices  = (const int*)d_in[1];
    const int*   segment_ids   = (const int*)d_in[2];
    float*       out           = (float*)d_out;

    const int B = 512;
    const int N = in_sizes[0] / B;      // 10000
    const int T = in_sizes[1];          // 131072
    const int G = out_size / B;         // 2048

    size_t featT_bytes = (size_t)N * B * sizeof(unsigned short);
    size_t need = featT_bytes + (size_t)(G + 1) * sizeof(int);
    int nTiles = (N + 63) / 64;  // 157
    if (ws_size >= need && B == 512 && (G % 8) == 0 && T >= 1 &&
        nTiles * 8 <= 2048 && nTiles >= 157) {
        unsigned short* featT = (unsigned short*)d_ws;            // (N, 512) bf16
        int* offs = (int*)((char*)d_ws + featT_bytes);            // (G+1,)

        pa_prep<<<1024, 256, 0, stream>>>(feat, segment_ids, featT, offs,
                                          N, T, G, nTiles);

        pa_gather_mean_bf16<<<(G / 8) * 8, 256, 0, stream>>>(featT, flat_indices, offs,
                                                             out, G);
    } else {
        pa_group_mean_direct<<<G, 256, 0, stream>>>(feat, flat_indices, segment_ids,
                                                    out, T, B, N, G);
    }
}